// Round 1
// baseline (7510.536 us; speedup 1.0000x reference)
//
#include <hip/hip_runtime.h>
#include <cstdint>

#define N_NODES 524288
#define E_EDGES 8388608
#define F_IN 128
#define HID 8
#define B_GRAPHS 64
#define NPG (N_NODES / B_GRAPHS)

// ---------------- degree & normalization ----------------
__global__ void deg_kernel(const int* __restrict__ dst, int* __restrict__ deg) {
    int e = blockIdx.x * blockDim.x + threadIdx.x;
    if (e < E_EDGES) atomicAdd(&deg[dst[e]], 1);
}

__global__ void dis_kernel(const int* __restrict__ deg, float* __restrict__ dis) {
    int i = blockIdx.x * blockDim.x + threadIdx.x;
    if (i < N_NODES) dis[i] = rsqrtf((float)deg[i] + 1.0f);
}

// ---------------- hp = x @ W1  [N,128]x[128,8] ----------------
__global__ void mm1_kernel(const float* __restrict__ x, const float* __restrict__ W1,
                           float* __restrict__ hp) {
    __shared__ float w[F_IN * HID];
    for (int t = threadIdx.x; t < F_IN * HID; t += blockDim.x) w[t] = W1[t];
    __syncthreads();
    int row = blockIdx.x * blockDim.x + threadIdx.x;
    if (row >= N_NODES) return;
    const float4* xr = (const float4*)(x + (size_t)row * F_IN);
    float acc[HID] = {0.f,0.f,0.f,0.f,0.f,0.f,0.f,0.f};
    #pragma unroll 8
    for (int it = 0; it < F_IN / 4; ++it) {
        float4 xv = xr[it];
        const float* wr = &w[it * 4 * HID];
        #pragma unroll
        for (int j = 0; j < HID; ++j)
            acc[j] += xv.x * wr[j] + xv.y * wr[HID + j] + xv.z * wr[2 * HID + j] + xv.w * wr[3 * HID + j];
    }
    float4* o = (float4*)(hp + (size_t)row * HID);
    o[0] = make_float4(acc[0], acc[1], acc[2], acc[3]);
    o[1] = make_float4(acc[4], acc[5], acc[6], acc[7]);
}

// ---------------- edge aggregation, 8-wide ----------------
__global__ void edge8_kernel(const int* __restrict__ src, const int* __restrict__ dst,
                             const float* __restrict__ dis, const float* __restrict__ hp,
                             float* __restrict__ agg) {
    int e = blockIdx.x * blockDim.x + threadIdx.x;
    if (e >= E_EDGES) return;
    int s = src[e], d = dst[e];
    float nrm = dis[s] * dis[d];
    const float4* hv = (const float4*)(hp + (size_t)s * HID);
    float4 a = hv[0], b = hv[1];
    float* ad = agg + (size_t)d * HID;
    unsafeAtomicAdd(ad + 0, a.x * nrm);
    unsafeAtomicAdd(ad + 1, a.y * nrm);
    unsafeAtomicAdd(ad + 2, a.z * nrm);
    unsafeAtomicAdd(ad + 3, a.w * nrm);
    unsafeAtomicAdd(ad + 4, b.x * nrm);
    unsafeAtomicAdd(ad + 5, b.y * nrm);
    unsafeAtomicAdd(ad + 6, b.z * nrm);
    unsafeAtomicAdd(ad + 7, b.w * nrm);
}

// ---------------- finalize layer1: x1 = relu(agg + hp*dd + b1); hp <- x1@W2; agg <- 0
__global__ void fin1_kernel(const float* __restrict__ b1v, const float* __restrict__ W2,
                            const float* __restrict__ dis, float* __restrict__ agg,
                            float* __restrict__ hp, float* __restrict__ x1) {
    __shared__ float w[HID * HID];
    __shared__ float bb[HID];
    if (threadIdx.x < HID * HID) w[threadIdx.x] = W2[threadIdx.x];
    if (threadIdx.x < HID) bb[threadIdx.x] = b1v[threadIdx.x];
    __syncthreads();
    int i = blockIdx.x * blockDim.x + threadIdx.x;
    if (i >= N_NODES) return;
    float dd = dis[i]; dd *= dd;
    float4* ap = (float4*)(agg + (size_t)i * HID);
    float4 a0 = ap[0], a1 = ap[1];
    float4* hpp = (float4*)(hp + (size_t)i * HID);
    float4 h0 = hpp[0], h1 = hpp[1];
    float v[HID];
    v[0] = fmaxf(a0.x + h0.x * dd + bb[0], 0.f);
    v[1] = fmaxf(a0.y + h0.y * dd + bb[1], 0.f);
    v[2] = fmaxf(a0.z + h0.z * dd + bb[2], 0.f);
    v[3] = fmaxf(a0.w + h0.w * dd + bb[3], 0.f);
    v[4] = fmaxf(a1.x + h1.x * dd + bb[4], 0.f);
    v[5] = fmaxf(a1.y + h1.y * dd + bb[5], 0.f);
    v[6] = fmaxf(a1.z + h1.z * dd + bb[6], 0.f);
    v[7] = fmaxf(a1.w + h1.w * dd + bb[7], 0.f);
    float4* xo = (float4*)(x1 + (size_t)i * HID);
    xo[0] = make_float4(v[0], v[1], v[2], v[3]);
    xo[1] = make_float4(v[4], v[5], v[6], v[7]);
    float o[HID];
    #pragma unroll
    for (int j = 0; j < HID; ++j) {
        float s = 0.f;
        #pragma unroll
        for (int k = 0; k < HID; ++k) s += v[k] * w[k * HID + j];
        o[j] = s;
    }
    hpp[0] = make_float4(o[0], o[1], o[2], o[3]);
    hpp[1] = make_float4(o[4], o[5], o[6], o[7]);
    float4 z4 = make_float4(0.f, 0.f, 0.f, 0.f);
    ap[0] = z4; ap[1] = z4;
}

// ---------------- finalize layer2: x2 = relu(agg + hp*dd + b2); agg <- 0
__global__ void fin2_kernel(const float* __restrict__ b2v, const float* __restrict__ dis,
                            float* __restrict__ agg, const float* __restrict__ hp,
                            float* __restrict__ x2) {
    __shared__ float bb[HID];
    if (threadIdx.x < HID) bb[threadIdx.x] = b2v[threadIdx.x];
    __syncthreads();
    int i = blockIdx.x * blockDim.x + threadIdx.x;
    if (i >= N_NODES) return;
    float dd = dis[i]; dd *= dd;
    float4* ap = (float4*)(agg + (size_t)i * HID);
    float4 a0 = ap[0], a1 = ap[1];
    const float4* hpp = (const float4*)(hp + (size_t)i * HID);
    float4 h0 = hpp[0], h1 = hpp[1];
    float4 r0, r1;
    r0.x = fmaxf(a0.x + h0.x * dd + bb[0], 0.f);
    r0.y = fmaxf(a0.y + h0.y * dd + bb[1], 0.f);
    r0.z = fmaxf(a0.z + h0.z * dd + bb[2], 0.f);
    r0.w = fmaxf(a0.w + h0.w * dd + bb[3], 0.f);
    r1.x = fmaxf(a1.x + h1.x * dd + bb[4], 0.f);
    r1.y = fmaxf(a1.y + h1.y * dd + bb[5], 0.f);
    r1.z = fmaxf(a1.z + h1.z * dd + bb[6], 0.f);
    r1.w = fmaxf(a1.w + h1.w * dd + bb[7], 0.f);
    float4* xo = (float4*)(x2 + (size_t)i * HID);
    xo[0] = r0; xo[1] = r1;
    float4 z4 = make_float4(0.f, 0.f, 0.f, 0.f);
    ap[0] = z4; ap[1] = z4;
}

// ---------------- target flags ----------------
__global__ void flag_kernel(const int* __restrict__ tid, unsigned char* __restrict__ flag) {
    int g = threadIdx.x;
    if (g < B_GRAPHS) flag[(size_t)g * NPG + tid[g]] = 1;
}

// ---------------- layer-3 edge pass, filtered to target dsts ----------------
__global__ void edge3_kernel(const int* __restrict__ src, const int* __restrict__ dst,
                             const unsigned char* __restrict__ flag,
                             const float* __restrict__ dis, const float* __restrict__ x2,
                             const float* __restrict__ W3, float* __restrict__ agg1) {
    int e = blockIdx.x * blockDim.x + threadIdx.x;
    if (e >= E_EDGES) return;
    int d = dst[e];
    if (!flag[d]) return;
    int s = src[e];
    float nrm = dis[s] * dis[d];
    const float4* xv = (const float4*)(x2 + (size_t)s * HID);
    float4 a = xv[0], b = xv[1];
    float h = a.x * W3[0] + a.y * W3[1] + a.z * W3[2] + a.w * W3[3]
            + b.x * W3[4] + b.y * W3[5] + b.z * W3[6] + b.w * W3[7];
    unsafeAtomicAdd(&agg1[d], h * nrm);
}

// ---------------- readout head: one lane per graph ----------------
__global__ void head_kernel(const int* __restrict__ tid, const float* __restrict__ x1,
                            const float* __restrict__ x2, const float* __restrict__ agg1,
                            const float* __restrict__ dis, const float* __restrict__ W3,
                            const float* __restrict__ b3, const float* __restrict__ Wl1,
                            const float* __restrict__ bl1, const float* __restrict__ Wl2,
                            const float* __restrict__ bl2, float* __restrict__ out) {
    int g = threadIdx.x;
    if (g >= B_GRAPHS) return;
    size_t node = (size_t)g * NPG + tid[g];
    float f[17];
    #pragma unroll
    for (int j = 0; j < HID; ++j) f[j] = x1[node * HID + j];
    #pragma unroll
    for (int j = 0; j < HID; ++j) f[8 + j] = x2[node * HID + j];
    float dd = dis[node]; dd *= dd;
    float h3 = 0.f;
    #pragma unroll
    for (int j = 0; j < HID; ++j) h3 += f[8 + j] * W3[j];
    f[16] = fmaxf(agg1[node] + h3 * dd + b3[0], 0.f);
    float o0 = bl2[0], o1 = bl2[1];
    #pragma unroll
    for (int j = 0; j < 16; ++j) {
        float z = bl1[j];
        #pragma unroll
        for (int k = 0; k < 17; ++k) z += f[k] * Wl1[k * 16 + j];
        z = fmaxf(z, 0.f);
        o0 += z * Wl2[j * 2 + 0];
        o1 += z * Wl2[j * 2 + 1];
    }
    out[g * 2 + 0] = o0;
    out[g * 2 + 1] = o1;
}

extern "C" void kernel_launch(void* const* d_in, const int* in_sizes, int n_in,
                              void* d_out, int out_size, void* d_ws, size_t ws_size,
                              hipStream_t stream) {
    const float* x  = (const float*)d_in[0];
    const int* ei   = (const int*)d_in[1];
    const int* src  = ei;
    const int* dst  = ei + E_EDGES;
    const int* tid  = (const int*)d_in[2];
    const float* W1 = (const float*)d_in[3];
    const float* b1 = (const float*)d_in[4];
    const float* W2 = (const float*)d_in[5];
    const float* b2 = (const float*)d_in[6];
    const float* W3 = (const float*)d_in[7];
    const float* b3 = (const float*)d_in[8];
    const float* Wl1 = (const float*)d_in[9];
    const float* bl1 = (const float*)d_in[10];
    const float* Wl2 = (const float*)d_in[11];
    const float* bl2 = (const float*)d_in[12];
    float* out = (float*)d_out;

    char* ws = (char*)d_ws;
    size_t off = 0;
    int* deg = (int*)(ws + off);            off += (size_t)N_NODES * 4;
    float* dis = (float*)(ws + off);        off += (size_t)N_NODES * 4;
    float* hp  = (float*)(ws + off);        off += (size_t)N_NODES * HID * 4;
    float* agg = (float*)(ws + off);        off += (size_t)N_NODES * HID * 4;
    float* x1  = (float*)(ws + off);        off += (size_t)N_NODES * HID * 4;
    float* x2  = (float*)(ws + off);        off += (size_t)N_NODES * HID * 4;
    unsigned char* flag = (unsigned char*)(ws + off); off += N_NODES;

    hipMemsetAsync(deg, 0, (size_t)N_NODES * 4, stream);
    hipMemsetAsync(agg, 0, (size_t)N_NODES * HID * 4, stream);
    hipMemsetAsync(flag, 0, N_NODES, stream);

    const int BLK = 256;
    const int EGRID = E_EDGES / BLK;
    const int NGRID = N_NODES / BLK;

    deg_kernel<<<EGRID, BLK, 0, stream>>>(dst, deg);
    dis_kernel<<<NGRID, BLK, 0, stream>>>(deg, dis);
    mm1_kernel<<<NGRID, BLK, 0, stream>>>(x, W1, hp);
    edge8_kernel<<<EGRID, BLK, 0, stream>>>(src, dst, dis, hp, agg);
    fin1_kernel<<<NGRID, BLK, 0, stream>>>(b1, W2, dis, agg, hp, x1);
    edge8_kernel<<<EGRID, BLK, 0, stream>>>(src, dst, dis, hp, agg);
    fin2_kernel<<<NGRID, BLK, 0, stream>>>(b2, dis, agg, hp, x2);
    flag_kernel<<<1, 64, 0, stream>>>(tid, flag);
    edge3_kernel<<<EGRID, BLK, 0, stream>>>(src, dst, flag, dis, x2, W3, agg);
    head_kernel<<<1, 64, 0, stream>>>(tid, x1, x2, agg, dis, W3, b3, Wl1, bl1, Wl2, bl2, out);
}

// Round 2
// 1957.301 us; speedup vs baseline: 3.8372x; 3.8372x over previous
//
#include <hip/hip_runtime.h>
#include <cstdint>

#define N_NODES 524288
#define E_EDGES 8388608
#define F_IN 128
#define HID 8
#define B_GRAPHS 64
#define NPG (N_NODES / B_GRAPHS)
#define NBLK 2048   // N_NODES / 256

// ---------------- degree count (int atomics, 4B RMW) ----------------
__global__ void deg_kernel(const int* __restrict__ dst, int* __restrict__ deg) {
    int e = blockIdx.x * blockDim.x + threadIdx.x;
    if (e < E_EDGES) atomicAdd(&deg[dst[e]], 1);
}

__global__ void dis_kernel(const int* __restrict__ deg, float* __restrict__ dis) {
    int i = blockIdx.x * blockDim.x + threadIdx.x;
    if (i < N_NODES) dis[i] = rsqrtf((float)deg[i] + 1.0f);
}

// ---------------- scan level 1: per-block (256) sums ----------------
__global__ void bsum_kernel(const int* __restrict__ deg, int* __restrict__ bsum) {
    __shared__ int sh[256];
    int t = threadIdx.x;
    sh[t] = deg[blockIdx.x * 256 + t];
    __syncthreads();
    for (int o = 128; o > 0; o >>= 1) {
        if (t < o) sh[t] += sh[t + o];
        __syncthreads();
    }
    if (t == 0) bsum[blockIdx.x] = sh[0];
}

// ---------------- scan level 2: exclusive scan of 2048 block sums (1 block) ----
__global__ void scan_bsum_kernel(int* __restrict__ bsum) {
    __shared__ int tsum[256];
    int t = threadIdx.x;
    int loc[8];
    int s = 0;
    #pragma unroll
    for (int k = 0; k < 8; ++k) {
        int v = bsum[t * 8 + k];
        loc[k] = s;
        s += v;
    }
    tsum[t] = s;
    __syncthreads();
    for (int o = 1; o < 256; o <<= 1) {
        int y = (t >= o) ? tsum[t - o] : 0;
        __syncthreads();
        tsum[t] += y;
        __syncthreads();
    }
    int off = (t == 0) ? 0 : tsum[t - 1];
    #pragma unroll
    for (int k = 0; k < 8; ++k) bsum[t * 8 + k] = off + loc[k];
}

// ---------------- scan level 3: rowptr[i] = global exclusive prefix ----------
__global__ void rowptr_kernel(const int* __restrict__ deg, const int* __restrict__ bsum,
                              int* __restrict__ rowptr) {
    __shared__ int sh[256];
    int t = threadIdx.x, b = blockIdx.x;
    int d = deg[b * 256 + t];
    sh[t] = d;
    __syncthreads();
    for (int o = 1; o < 256; o <<= 1) {
        int y = (t >= o) ? sh[t - o] : 0;
        __syncthreads();
        sh[t] += y;
        __syncthreads();
    }
    rowptr[b * 256 + t] = bsum[b] + sh[t] - d;   // exclusive
}

// ---------------- bucket fill: csr[slot] = src; rowptr becomes "end" --------
__global__ void fill_kernel(const int* __restrict__ src, const int* __restrict__ dst,
                            int* __restrict__ rowptr, int* __restrict__ csr) {
    int e = blockIdx.x * blockDim.x + threadIdx.x;
    if (e >= E_EDGES) return;
    int d = dst[e];
    int pos = atomicAdd(&rowptr[d], 1);
    csr[pos] = src[e];
}

// ---------------- hp = x @ W1  [N,128]x[128,8] ----------------
__global__ void mm1_kernel(const float* __restrict__ x, const float* __restrict__ W1,
                           float* __restrict__ hp) {
    __shared__ float w[F_IN * HID];
    for (int t = threadIdx.x; t < F_IN * HID; t += blockDim.x) w[t] = W1[t];
    __syncthreads();
    int row = blockIdx.x * blockDim.x + threadIdx.x;
    if (row >= N_NODES) return;
    const float4* xr = (const float4*)(x + (size_t)row * F_IN);
    float acc[HID] = {0.f,0.f,0.f,0.f,0.f,0.f,0.f,0.f};
    #pragma unroll 8
    for (int it = 0; it < F_IN / 4; ++it) {
        float4 xv = xr[it];
        const float* wr = &w[it * 4 * HID];
        #pragma unroll
        for (int j = 0; j < HID; ++j)
            acc[j] += xv.x * wr[j] + xv.y * wr[HID + j] + xv.z * wr[2 * HID + j] + xv.w * wr[3 * HID + j];
    }
    float4* o = (float4*)(hp + (size_t)row * HID);
    o[0] = make_float4(acc[0], acc[1], acc[2], acc[3]);
    o[1] = make_float4(acc[4], acc[5], acc[6], acc[7]);
}

// ---------------- gather layer1 fused: hp2 = relu(agg + self + b1) @ W2 ------
__global__ void gather1_kernel(const int* __restrict__ rowptr, const int* __restrict__ deg,
                               const int* __restrict__ csr, const float* __restrict__ dis,
                               const float* __restrict__ hp, const float* __restrict__ b1v,
                               const float* __restrict__ W2, float* __restrict__ hp2) {
    __shared__ float w[HID * HID];
    __shared__ float bb[HID];
    if (threadIdx.x < HID * HID) w[threadIdx.x] = W2[threadIdx.x];
    if (threadIdx.x < HID) bb[threadIdx.x] = b1v[threadIdx.x];
    __syncthreads();
    int i = blockIdx.x * blockDim.x + threadIdx.x;
    float di = dis[i];
    int end = rowptr[i];
    int n = deg[i];
    float acc[HID] = {0.f,0.f,0.f,0.f,0.f,0.f,0.f,0.f};
    for (int k = end - n; k < end; ++k) {
        int s = csr[k];
        float nrm = dis[s] * di;
        const float4* hv = (const float4*)(hp + (size_t)s * HID);
        float4 a = hv[0], b = hv[1];
        acc[0] += a.x * nrm; acc[1] += a.y * nrm; acc[2] += a.z * nrm; acc[3] += a.w * nrm;
        acc[4] += b.x * nrm; acc[5] += b.y * nrm; acc[6] += b.z * nrm; acc[7] += b.w * nrm;
    }
    float dd = di * di;
    const float4* hs = (const float4*)(hp + (size_t)i * HID);
    float4 h0 = hs[0], h1 = hs[1];
    float v[HID];
    v[0] = fmaxf(acc[0] + h0.x * dd + bb[0], 0.f);
    v[1] = fmaxf(acc[1] + h0.y * dd + bb[1], 0.f);
    v[2] = fmaxf(acc[2] + h0.z * dd + bb[2], 0.f);
    v[3] = fmaxf(acc[3] + h0.w * dd + bb[3], 0.f);
    v[4] = fmaxf(acc[4] + h1.x * dd + bb[4], 0.f);
    v[5] = fmaxf(acc[5] + h1.y * dd + bb[5], 0.f);
    v[6] = fmaxf(acc[6] + h1.z * dd + bb[6], 0.f);
    v[7] = fmaxf(acc[7] + h1.w * dd + bb[7], 0.f);
    float o[HID];
    #pragma unroll
    for (int j = 0; j < HID; ++j) {
        float s = 0.f;
        #pragma unroll
        for (int k = 0; k < HID; ++k) s += v[k] * w[k * HID + j];
        o[j] = s;
    }
    float4* op = (float4*)(hp2 + (size_t)i * HID);
    op[0] = make_float4(o[0], o[1], o[2], o[3]);
    op[1] = make_float4(o[4], o[5], o[6], o[7]);
}

// ---------------- gather layer2: x2 = relu(agg + self + b2) ----------------
__global__ void gather2_kernel(const int* __restrict__ rowptr, const int* __restrict__ deg,
                               const int* __restrict__ csr, const float* __restrict__ dis,
                               const float* __restrict__ hp2, const float* __restrict__ b2v,
                               float* __restrict__ x2) {
    __shared__ float bb[HID];
    if (threadIdx.x < HID) bb[threadIdx.x] = b2v[threadIdx.x];
    __syncthreads();
    int i = blockIdx.x * blockDim.x + threadIdx.x;
    float di = dis[i];
    int end = rowptr[i];
    int n = deg[i];
    float acc[HID] = {0.f,0.f,0.f,0.f,0.f,0.f,0.f,0.f};
    for (int k = end - n; k < end; ++k) {
        int s = csr[k];
        float nrm = dis[s] * di;
        const float4* hv = (const float4*)(hp2 + (size_t)s * HID);
        float4 a = hv[0], b = hv[1];
        acc[0] += a.x * nrm; acc[1] += a.y * nrm; acc[2] += a.z * nrm; acc[3] += a.w * nrm;
        acc[4] += b.x * nrm; acc[5] += b.y * nrm; acc[6] += b.z * nrm; acc[7] += b.w * nrm;
    }
    float dd = di * di;
    const float4* hs = (const float4*)(hp2 + (size_t)i * HID);
    float4 h0 = hs[0], h1 = hs[1];
    float4 r0, r1;
    r0.x = fmaxf(acc[0] + h0.x * dd + bb[0], 0.f);
    r0.y = fmaxf(acc[1] + h0.y * dd + bb[1], 0.f);
    r0.z = fmaxf(acc[2] + h0.z * dd + bb[2], 0.f);
    r0.w = fmaxf(acc[3] + h0.w * dd + bb[3], 0.f);
    r1.x = fmaxf(acc[4] + h1.x * dd + bb[4], 0.f);
    r1.y = fmaxf(acc[5] + h1.y * dd + bb[5], 0.f);
    r1.z = fmaxf(acc[6] + h1.z * dd + bb[6], 0.f);
    r1.w = fmaxf(acc[7] + h1.w * dd + bb[7], 0.f);
    float4* xo = (float4*)(x2 + (size_t)i * HID);
    xo[0] = r0; xo[1] = r1;
}

// ---------------- head: recompute x1[target] + layer3 gather + MLP ----------
__global__ void head_kernel(const int* __restrict__ tid, const int* __restrict__ rowptr,
                            const int* __restrict__ deg, const int* __restrict__ csr,
                            const float* __restrict__ dis, const float* __restrict__ hp,
                            const float* __restrict__ x2, const float* __restrict__ b1v,
                            const float* __restrict__ W3, const float* __restrict__ b3,
                            const float* __restrict__ Wl1, const float* __restrict__ bl1,
                            const float* __restrict__ Wl2, const float* __restrict__ bl2,
                            float* __restrict__ out) {
    int g = threadIdx.x;
    if (g >= B_GRAPHS) return;
    size_t node = (size_t)g * NPG + tid[g];
    float dn = dis[node];
    float dd = dn * dn;
    int end = rowptr[node];
    int n = deg[node];
    int start = end - n;
    float f[17];
    // layer-1 features at target: gather hp over in-neighbors
    float a1[HID] = {0.f,0.f,0.f,0.f,0.f,0.f,0.f,0.f};
    for (int k = start; k < end; ++k) {
        int s = csr[k];
        float nrm = dis[s] * dn;
        #pragma unroll
        for (int j = 0; j < HID; ++j) a1[j] += hp[(size_t)s * HID + j] * nrm;
    }
    #pragma unroll
    for (int j = 0; j < HID; ++j)
        f[j] = fmaxf(a1[j] + hp[node * HID + j] * dd + b1v[j], 0.f);
    // layer-2 features: already materialized
    #pragma unroll
    for (int j = 0; j < HID; ++j) f[8 + j] = x2[node * HID + j];
    // layer-3: gather x2 . W3 over in-neighbors
    float w3[HID];
    #pragma unroll
    for (int j = 0; j < HID; ++j) w3[j] = W3[j];
    float a3 = 0.f;
    for (int k = start; k < end; ++k) {
        int s = csr[k];
        float nrm = dis[s] * dn;
        float h = 0.f;
        #pragma unroll
        for (int j = 0; j < HID; ++j) h += x2[(size_t)s * HID + j] * w3[j];
        a3 += h * nrm;
    }
    float h3 = 0.f;
    #pragma unroll
    for (int j = 0; j < HID; ++j) h3 += f[8 + j] * w3[j];
    f[16] = fmaxf(a3 + h3 * dd + b3[0], 0.f);
    // MLP head
    float o0 = bl2[0], o1 = bl2[1];
    #pragma unroll
    for (int j = 0; j < 16; ++j) {
        float z = bl1[j];
        #pragma unroll
        for (int k = 0; k < 17; ++k) z += f[k] * Wl1[k * 16 + j];
        z = fmaxf(z, 0.f);
        o0 += z * Wl2[j * 2 + 0];
        o1 += z * Wl2[j * 2 + 1];
    }
    out[g * 2 + 0] = o0;
    out[g * 2 + 1] = o1;
}

extern "C" void kernel_launch(void* const* d_in, const int* in_sizes, int n_in,
                              void* d_out, int out_size, void* d_ws, size_t ws_size,
                              hipStream_t stream) {
    const float* x  = (const float*)d_in[0];
    const int* ei   = (const int*)d_in[1];
    const int* src  = ei;
    const int* dst  = ei + E_EDGES;
    const int* tid  = (const int*)d_in[2];
    const float* W1 = (const float*)d_in[3];
    const float* b1 = (const float*)d_in[4];
    const float* W2 = (const float*)d_in[5];
    const float* b2 = (const float*)d_in[6];
    const float* W3 = (const float*)d_in[7];
    const float* b3 = (const float*)d_in[8];
    const float* Wl1 = (const float*)d_in[9];
    const float* bl1 = (const float*)d_in[10];
    const float* Wl2 = (const float*)d_in[11];
    const float* bl2 = (const float*)d_in[12];
    float* out = (float*)d_out;

    char* ws = (char*)d_ws;
    size_t off = 0;
    int* deg = (int*)(ws + off);      off += (size_t)N_NODES * 4;       // 2 MB
    float* dis = (float*)(ws + off);  off += (size_t)N_NODES * 4;       // 2 MB
    int* rowptr = (int*)(ws + off);   off += (size_t)N_NODES * 4;       // 2 MB
    int* bsum = (int*)(ws + off);     off += (size_t)NBLK * 4;          // 8 KB
    int* csr = (int*)(ws + off);      off += (size_t)E_EDGES * 4;       // 33.5 MB
    float* hp = (float*)(ws + off);   off += (size_t)N_NODES * HID * 4; // 16 MB
    float* hp2 = (float*)(ws + off);  off += (size_t)N_NODES * HID * 4; // 16 MB
    float* x2 = (float*)(ws + off);   off += (size_t)N_NODES * HID * 4; // 16 MB

    hipMemsetAsync(deg, 0, (size_t)N_NODES * 4, stream);

    const int BLK = 256;
    const int EGRID = E_EDGES / BLK;

    deg_kernel<<<EGRID, BLK, 0, stream>>>(dst, deg);
    dis_kernel<<<NBLK, BLK, 0, stream>>>(deg, dis);
    bsum_kernel<<<NBLK, BLK, 0, stream>>>(deg, bsum);
    scan_bsum_kernel<<<1, 256, 0, stream>>>(bsum);
    rowptr_kernel<<<NBLK, BLK, 0, stream>>>(deg, bsum, rowptr);
    fill_kernel<<<EGRID, BLK, 0, stream>>>(src, dst, rowptr, csr);
    mm1_kernel<<<NBLK, BLK, 0, stream>>>(x, W1, hp);
    gather1_kernel<<<NBLK, BLK, 0, stream>>>(rowptr, deg, csr, dis, hp, b1, W2, hp2);
    gather2_kernel<<<NBLK, BLK, 0, stream>>>(rowptr, deg, csr, dis, hp2, b2, x2);
    head_kernel<<<1, 64, 0, stream>>>(tid, rowptr, deg, csr, dis, hp, x2,
                                      b1, W3, b3, Wl1, bl1, Wl2, bl2, out);
}

// Round 3
// 1258.950 us; speedup vs baseline: 5.9657x; 1.5547x over previous
//
#include <hip/hip_runtime.h>
#include <cstdint>

#define N_NODES 524288
#define E_EDGES 8388608
#define F_IN 128
#define HID 8
#define B_GRAPHS 64
#define NPG (N_NODES / B_GRAPHS)
#define NBLK 2048          // N_NODES / 256

// CSR build config
#define BUCKETS 1024       // coarse buckets (dst >> 9)
#define BSHIFT 9
#define BMASK 511
#define BUCKET_NODES 512   // N_NODES / BUCKETS
#define ABLK 512           // phase-A blocks
#define ATHREADS 512
#define EPB (E_EDGES / ABLK)   // 16384 edges per phase-A block

// ---------------- A1: per-block coarse histogram ----------------
__global__ void hist_kernel(const int* __restrict__ dst, int* __restrict__ M) {
    __shared__ int h[BUCKETS];
    int t = threadIdx.x;
    for (int j = t; j < BUCKETS; j += ATHREADS) h[j] = 0;
    __syncthreads();
    int base = blockIdx.x * EPB;
    #pragma unroll 4
    for (int k = 0; k < EPB / ATHREADS; ++k) {
        int d = dst[base + k * ATHREADS + t];
        atomicAdd(&h[d >> BSHIFT], 1);
    }
    __syncthreads();
    for (int j = t; j < BUCKETS; j += ATHREADS)
        M[(size_t)j * ABLK + blockIdx.x] = h[j];
}

// ---------------- A2: exclusive scan of each bucket row (over blocks) -------
__global__ void rowscan_kernel(int* __restrict__ M, int* __restrict__ btot) {
    __shared__ int tsum[256];
    int t = threadIdx.x;
    int* row = M + (size_t)blockIdx.x * ABLK;
    int v0 = row[t * 2], v1 = row[t * 2 + 1];
    int s = v0 + v1;
    tsum[t] = s;
    __syncthreads();
    for (int o = 1; o < 256; o <<= 1) {
        int y = (t >= o) ? tsum[t - o] : 0;
        __syncthreads();
        tsum[t] += y;
        __syncthreads();
    }
    int off = (t == 0) ? 0 : tsum[t - 1];
    row[t * 2] = off;
    row[t * 2 + 1] = off + v0;
    if (t == 255) btot[blockIdx.x] = off + s;
}

// ---------------- A3: exclusive scan of bucket totals -> bucket base --------
__global__ void basescan_kernel(const int* __restrict__ btot, int* __restrict__ base) {
    __shared__ int tsum[256];
    int t = threadIdx.x;
    int v[4], loc[4];
    int s = 0;
    #pragma unroll
    for (int k = 0; k < 4; ++k) {
        v[k] = btot[t * 4 + k];
        loc[k] = s;
        s += v[k];
    }
    tsum[t] = s;
    __syncthreads();
    for (int o = 1; o < 256; o <<= 1) {
        int y = (t >= o) ? tsum[t - o] : 0;
        __syncthreads();
        tsum[t] += y;
        __syncthreads();
    }
    int off = (t == 0) ? 0 : tsum[t - 1];
    #pragma unroll
    for (int k = 0; k < 4; ++k) base[t * 4 + k] = off + loc[k];
    if (t == 255) base[BUCKETS] = off + s;   // == E_EDGES
}

// ---------------- A4: bucket scatter via LDS cursors (no global atomics) ----
__global__ void scatter_kernel(const int* __restrict__ src, const int* __restrict__ dst,
                               const int* __restrict__ M, const int* __restrict__ base,
                               unsigned int* __restrict__ ebuf) {
    __shared__ int cur[BUCKETS];
    int t = threadIdx.x;
    for (int j = t; j < BUCKETS; j += ATHREADS)
        cur[j] = base[j] + M[(size_t)j * ABLK + blockIdx.x];
    __syncthreads();
    int eb = blockIdx.x * EPB;
    for (int k = 0; k < EPB / ATHREADS; ++k) {
        int e = eb + k * ATHREADS + t;
        int d = dst[e];
        int s = src[e];
        int p = atomicAdd(&cur[d >> BSHIFT], 1);
        ebuf[p] = ((unsigned int)(d & BMASK) << 19) | (unsigned int)s;
    }
}

// ---------------- B: per-bucket fine counting sort -> rowptr, dis, csr ------
__global__ __launch_bounds__(256) void build_kernel(const unsigned int* __restrict__ ebuf,
                                                    const int* __restrict__ base,
                                                    int* __restrict__ rowptr,
                                                    float* __restrict__ dis,
                                                    int* __restrict__ csr) {
    __shared__ int cnt[BUCKET_NODES];
    __shared__ int cur[BUCKET_NODES];
    __shared__ int tsum[256];
    int t = threadIdx.x;
    int b = blockIdx.x;
    int e0 = base[b], e1 = base[b + 1];
    int n = e1 - e0;
    cnt[t] = 0; cnt[t + 256] = 0;
    __syncthreads();
    for (int k = t; k < n; k += 256)
        atomicAdd(&cnt[ebuf[e0 + k] >> 19], 1);
    __syncthreads();
    // exclusive scan of 512 bins, 2 per thread
    int v0 = cnt[t * 2], v1 = cnt[t * 2 + 1];
    int s = v0 + v1;
    tsum[t] = s;
    __syncthreads();
    for (int o = 1; o < 256; o <<= 1) {
        int y = (t >= o) ? tsum[t - o] : 0;
        __syncthreads();
        tsum[t] += y;
        __syncthreads();
    }
    int off = (t == 0) ? 0 : tsum[t - 1];
    cur[t * 2] = off;
    cur[t * 2 + 1] = off + v0;
    int nodeBase = b * BUCKET_NODES;
    rowptr[nodeBase + t * 2]     = e0 + off;
    rowptr[nodeBase + t * 2 + 1] = e0 + off + v0;
    dis[nodeBase + t * 2]     = rsqrtf((float)v0 + 1.0f);
    dis[nodeBase + t * 2 + 1] = rsqrtf((float)v1 + 1.0f);
    if (b == 0 && t == 0) rowptr[N_NODES] = E_EDGES;
    __syncthreads();
    for (int k = t; k < n; k += 256) {
        unsigned int w = ebuf[e0 + k];
        int lo = (int)(w >> 19);
        int p = atomicAdd(&cur[lo], 1);
        csr[e0 + p] = (int)(w & 0x7FFFFu);
    }
}

// ---------------- hp = x @ W1  [N,128]x[128,8] ----------------
__global__ void mm1_kernel(const float* __restrict__ x, const float* __restrict__ W1,
                           float* __restrict__ hp) {
    __shared__ float w[F_IN * HID];
    for (int t = threadIdx.x; t < F_IN * HID; t += blockDim.x) w[t] = W1[t];
    __syncthreads();
    int row = blockIdx.x * blockDim.x + threadIdx.x;
    if (row >= N_NODES) return;
    const float4* xr = (const float4*)(x + (size_t)row * F_IN);
    float acc[HID] = {0.f,0.f,0.f,0.f,0.f,0.f,0.f,0.f};
    #pragma unroll 8
    for (int it = 0; it < F_IN / 4; ++it) {
        float4 xv = xr[it];
        const float* wr = &w[it * 4 * HID];
        #pragma unroll
        for (int j = 0; j < HID; ++j)
            acc[j] += xv.x * wr[j] + xv.y * wr[HID + j] + xv.z * wr[2 * HID + j] + xv.w * wr[3 * HID + j];
    }
    float4* o = (float4*)(hp + (size_t)row * HID);
    o[0] = make_float4(acc[0], acc[1], acc[2], acc[3]);
    o[1] = make_float4(acc[4], acc[5], acc[6], acc[7]);
}

// ---------------- gather layer1 fused: hp2 = relu(agg + self + b1) @ W2 ------
__global__ void gather1_kernel(const int* __restrict__ rowptr, const int* __restrict__ csr,
                               const float* __restrict__ dis, const float* __restrict__ hp,
                               const float* __restrict__ b1v, const float* __restrict__ W2,
                               float* __restrict__ hp2) {
    __shared__ float w[HID * HID];
    __shared__ float bb[HID];
    if (threadIdx.x < HID * HID) w[threadIdx.x] = W2[threadIdx.x];
    if (threadIdx.x < HID) bb[threadIdx.x] = b1v[threadIdx.x];
    __syncthreads();
    int i = blockIdx.x * blockDim.x + threadIdx.x;
    float di = dis[i];
    int start = rowptr[i], end = rowptr[i + 1];
    float acc[HID] = {0.f,0.f,0.f,0.f,0.f,0.f,0.f,0.f};
    for (int k = start; k < end; ++k) {
        int s = csr[k];
        float nrm = dis[s] * di;
        const float4* hv = (const float4*)(hp + (size_t)s * HID);
        float4 a = hv[0], b = hv[1];
        acc[0] += a.x * nrm; acc[1] += a.y * nrm; acc[2] += a.z * nrm; acc[3] += a.w * nrm;
        acc[4] += b.x * nrm; acc[5] += b.y * nrm; acc[6] += b.z * nrm; acc[7] += b.w * nrm;
    }
    float dd = di * di;
    const float4* hs = (const float4*)(hp + (size_t)i * HID);
    float4 h0 = hs[0], h1 = hs[1];
    float v[HID];
    v[0] = fmaxf(acc[0] + h0.x * dd + bb[0], 0.f);
    v[1] = fmaxf(acc[1] + h0.y * dd + bb[1], 0.f);
    v[2] = fmaxf(acc[2] + h0.z * dd + bb[2], 0.f);
    v[3] = fmaxf(acc[3] + h0.w * dd + bb[3], 0.f);
    v[4] = fmaxf(acc[4] + h1.x * dd + bb[4], 0.f);
    v[5] = fmaxf(acc[5] + h1.y * dd + bb[5], 0.f);
    v[6] = fmaxf(acc[6] + h1.z * dd + bb[6], 0.f);
    v[7] = fmaxf(acc[7] + h1.w * dd + bb[7], 0.f);
    float o[HID];
    #pragma unroll
    for (int j = 0; j < HID; ++j) {
        float sj = 0.f;
        #pragma unroll
        for (int k = 0; k < HID; ++k) sj += v[k] * w[k * HID + j];
        o[j] = sj;
    }
    float4* op = (float4*)(hp2 + (size_t)i * HID);
    op[0] = make_float4(o[0], o[1], o[2], o[3]);
    op[1] = make_float4(o[4], o[5], o[6], o[7]);
}

// ---------------- gather layer2: x2 = relu(agg + self + b2) ----------------
__global__ void gather2_kernel(const int* __restrict__ rowptr, const int* __restrict__ csr,
                               const float* __restrict__ dis, const float* __restrict__ hp2,
                               const float* __restrict__ b2v, float* __restrict__ x2) {
    __shared__ float bb[HID];
    if (threadIdx.x < HID) bb[threadIdx.x] = b2v[threadIdx.x];
    __syncthreads();
    int i = blockIdx.x * blockDim.x + threadIdx.x;
    float di = dis[i];
    int start = rowptr[i], end = rowptr[i + 1];
    float acc[HID] = {0.f,0.f,0.f,0.f,0.f,0.f,0.f,0.f};
    for (int k = start; k < end; ++k) {
        int s = csr[k];
        float nrm = dis[s] * di;
        const float4* hv = (const float4*)(hp2 + (size_t)s * HID);
        float4 a = hv[0], b = hv[1];
        acc[0] += a.x * nrm; acc[1] += a.y * nrm; acc[2] += a.z * nrm; acc[3] += a.w * nrm;
        acc[4] += b.x * nrm; acc[5] += b.y * nrm; acc[6] += b.z * nrm; acc[7] += b.w * nrm;
    }
    float dd = di * di;
    const float4* hs = (const float4*)(hp2 + (size_t)i * HID);
    float4 h0 = hs[0], h1 = hs[1];
    float4 r0, r1;
    r0.x = fmaxf(acc[0] + h0.x * dd + bb[0], 0.f);
    r0.y = fmaxf(acc[1] + h0.y * dd + bb[1], 0.f);
    r0.z = fmaxf(acc[2] + h0.z * dd + bb[2], 0.f);
    r0.w = fmaxf(acc[3] + h0.w * dd + bb[3], 0.f);
    r1.x = fmaxf(acc[4] + h1.x * dd + bb[4], 0.f);
    r1.y = fmaxf(acc[5] + h1.y * dd + bb[5], 0.f);
    r1.z = fmaxf(acc[6] + h1.z * dd + bb[6], 0.f);
    r1.w = fmaxf(acc[7] + h1.w * dd + bb[7], 0.f);
    float4* xo = (float4*)(x2 + (size_t)i * HID);
    xo[0] = r0; xo[1] = r1;
}

// ---------------- head: recompute x1[target] + layer3 gather + MLP ----------
__global__ void head_kernel(const int* __restrict__ tid, const int* __restrict__ rowptr,
                            const int* __restrict__ csr, const float* __restrict__ dis,
                            const float* __restrict__ hp, const float* __restrict__ x2,
                            const float* __restrict__ b1v, const float* __restrict__ W3,
                            const float* __restrict__ b3, const float* __restrict__ Wl1,
                            const float* __restrict__ bl1, const float* __restrict__ Wl2,
                            const float* __restrict__ bl2, float* __restrict__ out) {
    int g = threadIdx.x;
    if (g >= B_GRAPHS) return;
    size_t node = (size_t)g * NPG + tid[g];
    float dn = dis[node];
    float dd = dn * dn;
    int start = rowptr[node];
    int end = rowptr[node + 1];
    float f[17];
    float a1[HID] = {0.f,0.f,0.f,0.f,0.f,0.f,0.f,0.f};
    for (int k = start; k < end; ++k) {
        int s = csr[k];
        float nrm = dis[s] * dn;
        #pragma unroll
        for (int j = 0; j < HID; ++j) a1[j] += hp[(size_t)s * HID + j] * nrm;
    }
    #pragma unroll
    for (int j = 0; j < HID; ++j)
        f[j] = fmaxf(a1[j] + hp[node * HID + j] * dd + b1v[j], 0.f);
    #pragma unroll
    for (int j = 0; j < HID; ++j) f[8 + j] = x2[node * HID + j];
    float w3[HID];
    #pragma unroll
    for (int j = 0; j < HID; ++j) w3[j] = W3[j];
    float a3 = 0.f;
    for (int k = start; k < end; ++k) {
        int s = csr[k];
        float nrm = dis[s] * dn;
        float h = 0.f;
        #pragma unroll
        for (int j = 0; j < HID; ++j) h += x2[(size_t)s * HID + j] * w3[j];
        a3 += h * nrm;
    }
    float h3 = 0.f;
    #pragma unroll
    for (int j = 0; j < HID; ++j) h3 += f[8 + j] * w3[j];
    f[16] = fmaxf(a3 + h3 * dd + b3[0], 0.f);
    float o0 = bl2[0], o1 = bl2[1];
    #pragma unroll
    for (int j = 0; j < 16; ++j) {
        float z = bl1[j];
        #pragma unroll
        for (int k = 0; k < 17; ++k) z += f[k] * Wl1[k * 16 + j];
        z = fmaxf(z, 0.f);
        o0 += z * Wl2[j * 2 + 0];
        o1 += z * Wl2[j * 2 + 1];
    }
    out[g * 2 + 0] = o0;
    out[g * 2 + 1] = o1;
}

extern "C" void kernel_launch(void* const* d_in, const int* in_sizes, int n_in,
                              void* d_out, int out_size, void* d_ws, size_t ws_size,
                              hipStream_t stream) {
    const float* x  = (const float*)d_in[0];
    const int* ei   = (const int*)d_in[1];
    const int* src  = ei;
    const int* dst  = ei + E_EDGES;
    const int* tid  = (const int*)d_in[2];
    const float* W1 = (const float*)d_in[3];
    const float* b1 = (const float*)d_in[4];
    const float* W2 = (const float*)d_in[5];
    const float* b2 = (const float*)d_in[6];
    const float* W3 = (const float*)d_in[7];
    const float* b3 = (const float*)d_in[8];
    const float* Wl1 = (const float*)d_in[9];
    const float* bl1 = (const float*)d_in[10];
    const float* Wl2 = (const float*)d_in[11];
    const float* bl2 = (const float*)d_in[12];
    float* out = (float*)d_out;

    char* ws = (char*)d_ws;
    size_t off = 0;
    auto alloc = [&](size_t bytes) {
        void* p = ws + off;
        off += (bytes + 255) & ~(size_t)255;
        return p;
    };
    int* M        = (int*)alloc((size_t)BUCKETS * ABLK * 4);   // 2 MB
    int* btot     = (int*)alloc((size_t)BUCKETS * 4);          // 4 KB
    int* base     = (int*)alloc((size_t)(BUCKETS + 1) * 4);    // 4 KB
    int* rowptr   = (int*)alloc((size_t)(N_NODES + 1) * 4);    // 2 MB
    float* dis    = (float*)alloc((size_t)N_NODES * 4);        // 2 MB
    int* csr      = (int*)alloc((size_t)E_EDGES * 4);          // 33.5 MB
    // ebuf (33.5 MB) aliases the hp/hp2/x2 region (48 MB): ebuf dead before mm1 runs
    char* uni     = (char*)alloc((size_t)N_NODES * HID * 4 * 3);
    unsigned int* ebuf = (unsigned int*)uni;
    float* hp  = (float*)uni;
    float* hp2 = (float*)(uni + (size_t)N_NODES * HID * 4);
    float* x2  = (float*)(uni + (size_t)N_NODES * HID * 4 * 2);

    const int BLK = 256;

    hist_kernel<<<ABLK, ATHREADS, 0, stream>>>(dst, M);
    rowscan_kernel<<<BUCKETS, 256, 0, stream>>>(M, btot);
    basescan_kernel<<<1, 256, 0, stream>>>(btot, base);
    scatter_kernel<<<ABLK, ATHREADS, 0, stream>>>(src, dst, M, base, ebuf);
    build_kernel<<<BUCKETS, 256, 0, stream>>>(ebuf, base, rowptr, dis, csr);
    mm1_kernel<<<NBLK, BLK, 0, stream>>>(x, W1, hp);
    gather1_kernel<<<NBLK, BLK, 0, stream>>>(rowptr, csr, dis, hp, b1, W2, hp2);
    gather2_kernel<<<NBLK, BLK, 0, stream>>>(rowptr, csr, dis, hp2, b2, x2);
    head_kernel<<<1, 64, 0, stream>>>(tid, rowptr, csr, dis, hp, x2,
                                      b1, W3, b3, Wl1, bl1, Wl2, bl2, out);
}